// Round 1
// baseline (225.068 us; speedup 1.0000x reference)
//
#include <hip/hip_runtime.h>

#define KDIM   1200
#define NBITS  2400
#define BATCHN 16384
#define WPAD   20   // 19 used 64-bit words per row + 1 zero pad -> 160B rows, 16B aligned

// ---------- pack: one wave (64 lanes) per row, ballot-based bit packing ----------
__global__ __launch_bounds__(256) void pack_rows_int(const int* __restrict__ src,
                                                     unsigned long long* __restrict__ dst,
                                                     int rows, int cols) {
    int gtid = blockIdx.x * blockDim.x + threadIdx.x;
    int wave = gtid >> 6;
    int lane = gtid & 63;
    if (wave >= rows) return;
    const int* row = src + (size_t)wave * cols;
    unsigned long long* orow = dst + (size_t)wave * WPAD;
    #pragma unroll
    for (int j = 0; j < WPAD; ++j) {
        int idx = j * 64 + lane;
        int v = (idx < cols) ? row[idx] : 0;
        unsigned long long mask = __ballot(v != 0);
        if (lane == 0) orow[j] = mask;
    }
}

__global__ __launch_bounds__(256) void pack_rows_float(const float* __restrict__ src,
                                                       unsigned long long* __restrict__ dst,
                                                       int rows, int cols) {
    int gtid = blockIdx.x * blockDim.x + threadIdx.x;
    int wave = gtid >> 6;
    int lane = gtid & 63;
    if (wave >= rows) return;
    const float* row = src + (size_t)wave * cols;
    unsigned long long* orow = dst + (size_t)wave * WPAD;
    #pragma unroll
    for (int j = 0; j < WPAD; ++j) {
        int idx = j * 64 + lane;
        float v = (idx < cols) ? row[idx] : 0.0f;
        unsigned long long mask = __ballot(v != 0.0f);
        if (lane == 0) orow[j] = mask;
    }
}

// ---------- encode: lane = output column n, wave loops 64 batch rows ----------
__global__ __launch_bounds__(256) void ldpc_encode(const unsigned long long* __restrict__ mp,
                                                   const unsigned long long* __restrict__ gp,
                                                   float* __restrict__ out) {
    const int lane = threadIdx.x & 63;
    const int wv   = threadIdx.x >> 6;            // 0..3
    const int n    = blockIdx.x * 64 + lane;      // output column
    const bool nv  = (n < NBITS);

    // G row for this lane, in registers (20 u64 = 40 VGPRs)
    unsigned long long g[WPAD];
    {
        const ulonglong2* gr = (const ulonglong2*)(gp + (size_t)(nv ? n : 0) * WPAD);
        #pragma unroll
        for (int j = 0; j < WPAD / 2; ++j) {
            ulonglong2 t = gr[j];
            g[2 * j]     = t.x;
            g[2 * j + 1] = t.y;
        }
    }

    const int b0 = (blockIdx.y * 4 + wv) * 64;    // 64 batch rows per wave
    const ulonglong2* mr = (const ulonglong2*)(mp + (size_t)b0 * WPAD);
    float* orow = out + (size_t)b0 * NBITS + n;

    for (int bi = 0; bi < 64; ++bi) {
        int acc = 0;
        #pragma unroll
        for (int j = 0; j < WPAD / 2; ++j) {
            ulonglong2 t = mr[j];                 // wave-uniform address: L1 broadcast
            acc += __popcll(g[2 * j]     & t.x);
            acc += __popcll(g[2 * j + 1] & t.y);
        }
        if (nv) *orow = 1.0f - 2.0f * (float)(acc & 1);
        mr   += WPAD / 2;
        orow += NBITS;
    }
}

// ---------- fallback (only if workspace is too small): direct parity GEMM ----------
__global__ __launch_bounds__(256) void ldpc_naive(const int* __restrict__ m,
                                                  const float* __restrict__ G,
                                                  float* __restrict__ out) {
    long long idx = (long long)blockIdx.x * blockDim.x + threadIdx.x;
    if (idx >= (long long)BATCHN * NBITS) return;
    int b = (int)(idx / NBITS);
    int n = (int)(idx % NBITS);
    int acc = 0;
    const int*   mr = m + (size_t)b * KDIM;
    const float* gr = G + (size_t)n * KDIM;
    for (int k = 0; k < KDIM; ++k)
        acc ^= (mr[k] & (gr[k] != 0.0f ? 1 : 0));
    out[idx] = 1.0f - 2.0f * (float)acc;
}

extern "C" void kernel_launch(void* const* d_in, const int* in_sizes, int n_in,
                              void* d_out, int out_size, void* d_ws, size_t ws_size,
                              hipStream_t stream) {
    const int*   m = (const int*)d_in[0];    // [BATCHN, KDIM] int32 (0/1)
    const float* G = (const float*)d_in[1];  // [NBITS, KDIM]  f32   (0/1)
    float* out = (float*)d_out;              // [BATCHN, NBITS] f32

    const size_t need = ((size_t)BATCHN + NBITS) * WPAD * sizeof(unsigned long long);
    if (ws_size >= need) {
        unsigned long long* mp = (unsigned long long*)d_ws;
        unsigned long long* gp = mp + (size_t)BATCHN * WPAD;

        // one wave per row: rows*64 threads total
        pack_rows_int  <<<(BATCHN * 64) / 256, 256, 0, stream>>>(m, mp, BATCHN, KDIM);
        pack_rows_float<<<(NBITS  * 64) / 256, 256, 0, stream>>>(G, gp, NBITS, KDIM);

        dim3 grid((NBITS + 63) / 64, BATCHN / 256);  // (38, 64)
        ldpc_encode<<<grid, 256, 0, stream>>>(mp, gp, out);
    } else {
        long long total = (long long)BATCHN * NBITS;
        ldpc_naive<<<(int)((total + 255) / 256), 256, 0, stream>>>(m, G, out);
    }
}

// Round 2
// 155.757 us; speedup vs baseline: 1.4450x; 1.4450x over previous
//
#include <hip/hip_runtime.h>

#define KDIM   1200
#define NBITS  2400
#define BATCHN 16384
#define WPAD   20   // 19 used 64-bit words per row + 1 zero pad -> 160B rows, 16B aligned

// ---------- pack: one wave (64 lanes) per row, ballot-based bit packing ----------
__global__ __launch_bounds__(256) void pack_rows_int(const int* __restrict__ src,
                                                     unsigned long long* __restrict__ dst,
                                                     int rows, int cols) {
    int gtid = blockIdx.x * blockDim.x + threadIdx.x;
    int wave = gtid >> 6;
    int lane = gtid & 63;
    if (wave >= rows) return;
    const int* row = src + (size_t)wave * cols;
    unsigned long long* orow = dst + (size_t)wave * WPAD;
    #pragma unroll
    for (int j = 0; j < WPAD; ++j) {
        int idx = j * 64 + lane;
        int v = (idx < cols) ? row[idx] : 0;
        unsigned long long mask = __ballot(v != 0);
        if (lane == 0) orow[j] = mask;
    }
}

__global__ __launch_bounds__(256) void pack_rows_float(const float* __restrict__ src,
                                                       unsigned long long* __restrict__ dst,
                                                       int rows, int cols) {
    int gtid = blockIdx.x * blockDim.x + threadIdx.x;
    int wave = gtid >> 6;
    int lane = gtid & 63;
    if (wave >= rows) return;
    const float* row = src + (size_t)wave * cols;
    unsigned long long* orow = dst + (size_t)wave * WPAD;
    #pragma unroll
    for (int j = 0; j < WPAD; ++j) {
        int idx = j * 64 + lane;
        float v = (idx < cols) ? row[idx] : 0.0f;
        unsigned long long mask = __ballot(v != 0.0f);
        if (lane == 0) orow[j] = mask;
    }
}

// ---------- encode: lane owns 2 output columns; ping-pong prefetch over batch rows ----------
__global__ __launch_bounds__(256) void ldpc_encode(const unsigned long long* __restrict__ mp,
                                                   const unsigned long long* __restrict__ gp,
                                                   float* __restrict__ out) {
    const int lane = threadIdx.x & 63;
    const int wv   = threadIdx.x >> 6;            // 0..3
    const int n0   = blockIdx.x * 128 + lane;     // output columns n0, n0+64
    const int n1   = n0 + 64;
    const bool v0  = (n0 < NBITS);
    const bool v1  = (n1 < NBITS);

    // two G rows in registers (2 x 20 u64 = 80 VGPRs)
    ulonglong2 g0[WPAD / 2], g1[WPAD / 2];
    {
        const ulonglong2* gr0 = (const ulonglong2*)(gp + (size_t)(v0 ? n0 : 0) * WPAD);
        const ulonglong2* gr1 = (const ulonglong2*)(gp + (size_t)(v1 ? n1 : 0) * WPAD);
        #pragma unroll
        for (int j = 0; j < WPAD / 2; ++j) { g0[j] = gr0[j]; g1[j] = gr1[j]; }
    }

    const int b0 = (blockIdx.y * 4 + wv) * 64;    // 64 batch rows per wave
    const ulonglong2* mr = (const ulonglong2*)(mp + (size_t)b0 * WPAD);
    float* orow = out + (size_t)b0 * NBITS;

    auto compute_store = [&](const ulonglong2* t, float* optr) {
        int a0 = 0, a1 = 0;
        #pragma unroll
        for (int j = 0; j < 9; ++j) {
            a0 += __popcll(g0[j].x & t[j].x);
            a0 += __popcll(g0[j].y & t[j].y);
            a1 += __popcll(g1[j].x & t[j].x);
            a1 += __popcll(g1[j].y & t[j].y);
        }
        // pair 9 = words 18,19; word 19 is the zero pad -> only .x contributes
        a0 += __popcll(g0[9].x & t[9].x);
        a1 += __popcll(g1[9].x & t[9].x);
        if (v0) optr[n0] = __uint_as_float(0x3f800000u | ((unsigned)a0 << 31));
        if (v1) optr[n1] = __uint_as_float(0x3f800000u | ((unsigned)a1 << 31));
    };

    // software pipeline: ta/tb ping-pong, prefetch one row ahead.
    // Final iteration prefetches one row past this wave's range; worst case reads
    // the first row of gp (mp and gp are contiguous in d_ws) -> always in bounds.
    ulonglong2 ta[WPAD / 2], tb[WPAD / 2];
    #pragma unroll
    for (int j = 0; j < WPAD / 2; ++j) ta[j] = mr[j];
    const ulonglong2* mrp = mr + WPAD / 2;

    #pragma unroll 1
    for (int bi = 0; bi < 64; bi += 2) {
        #pragma unroll
        for (int j = 0; j < WPAD / 2; ++j) tb[j] = mrp[j];                 // row bi+1
        compute_store(ta, orow);                                           // row bi
        orow += NBITS;
        #pragma unroll
        for (int j = 0; j < WPAD / 2; ++j) ta[j] = mrp[WPAD / 2 + j];      // row bi+2
        compute_store(tb, orow);                                           // row bi+1
        orow += NBITS;
        mrp += WPAD;
    }
}

// ---------- fallback (only if workspace is too small): direct parity GEMM ----------
__global__ __launch_bounds__(256) void ldpc_naive(const int* __restrict__ m,
                                                  const float* __restrict__ G,
                                                  float* __restrict__ out) {
    long long idx = (long long)blockIdx.x * blockDim.x + threadIdx.x;
    if (idx >= (long long)BATCHN * NBITS) return;
    int b = (int)(idx / NBITS);
    int n = (int)(idx % NBITS);
    int acc = 0;
    const int*   mr = m + (size_t)b * KDIM;
    const float* gr = G + (size_t)n * KDIM;
    for (int k = 0; k < KDIM; ++k)
        acc ^= (mr[k] & (gr[k] != 0.0f ? 1 : 0));
    out[idx] = 1.0f - 2.0f * (float)acc;
}

extern "C" void kernel_launch(void* const* d_in, const int* in_sizes, int n_in,
                              void* d_out, int out_size, void* d_ws, size_t ws_size,
                              hipStream_t stream) {
    const int*   m = (const int*)d_in[0];    // [BATCHN, KDIM] int32 (0/1)
    const float* G = (const float*)d_in[1];  // [NBITS, KDIM]  f32   (0/1)
    float* out = (float*)d_out;              // [BATCHN, NBITS] f32

    const size_t need = ((size_t)BATCHN + NBITS) * WPAD * sizeof(unsigned long long);
    if (ws_size >= need) {
        unsigned long long* mp = (unsigned long long*)d_ws;
        unsigned long long* gp = mp + (size_t)BATCHN * WPAD;

        pack_rows_int  <<<(BATCHN * 64) / 256, 256, 0, stream>>>(m, mp, BATCHN, KDIM);
        pack_rows_float<<<(NBITS  * 64) / 256, 256, 0, stream>>>(G, gp, NBITS, KDIM);

        dim3 grid((NBITS + 127) / 128, BATCHN / 256);  // (19, 64)
        ldpc_encode<<<grid, 256, 0, stream>>>(mp, gp, out);
    } else {
        long long total = (long long)BATCHN * NBITS;
        ldpc_naive<<<(int)((total + 255) / 256), 256, 0, stream>>>(m, G, out);
    }
}

// Round 4
// 106.230 us; speedup vs baseline: 2.1187x; 1.4662x over previous
//
#include <hip/hip_runtime.h>

#define KDIM   1200
#define NBITS  2400
#define BATCHN 16384
#define WPAD   20   // 19 used 64-bit words per row + 1 zero pad -> 160B rows, 16B aligned
#define NDW    38   // meaningful 32-bit words per row (1200 bits -> 37.5 -> 38)
#define ROWS   16   // batch rows per block

// ---------- pack: one wave (64 lanes) per row, ballot-based bit packing ----------
__global__ __launch_bounds__(256) void pack_rows_int(const int* __restrict__ src,
                                                     unsigned long long* __restrict__ dst,
                                                     int rows, int cols) {
    int gtid = blockIdx.x * blockDim.x + threadIdx.x;
    int wave = gtid >> 6;
    int lane = gtid & 63;
    if (wave >= rows) return;
    const int* row = src + (size_t)wave * cols;
    unsigned long long* orow = dst + (size_t)wave * WPAD;
    #pragma unroll
    for (int j = 0; j < WPAD; ++j) {
        int idx = j * 64 + lane;
        int v = (idx < cols) ? row[idx] : 0;
        unsigned long long mask = __ballot(v != 0);
        if (lane == 0) orow[j] = mask;
    }
}

__global__ __launch_bounds__(256) void pack_rows_float(const float* __restrict__ src,
                                                       unsigned long long* __restrict__ dst,
                                                       int rows, int cols) {
    int gtid = blockIdx.x * blockDim.x + threadIdx.x;
    int wave = gtid >> 6;
    int lane = gtid & 63;
    if (wave >= rows) return;
    const float* row = src + (size_t)wave * cols;
    unsigned long long* orow = dst + (size_t)wave * WPAD;
    #pragma unroll
    for (int j = 0; j < WPAD; ++j) {
        int idx = j * 64 + lane;
        float v = (idx < cols) ? row[idx] : 0.0f;
        unsigned long long mask = __ballot(v != 0.0f);
        if (lane == 0) orow[j] = mask;
    }
}

// ---------- encode: 1 column/lane, block-uniform m-rows, XOR-parity ----------
// grid = (10, BATCHN/ROWS); block covers 256 columns x ROWS batch rows.
__global__ __launch_bounds__(256, 4) void ldpc_encode(const unsigned long long* __restrict__ mp,
                                                      const unsigned long long* __restrict__ gp,
                                                      float* __restrict__ out) {
    const int n  = blockIdx.x * 256 + threadIdx.x;   // output column
    const bool nv = (n < NBITS);

    // this lane's G row, 38 meaningful dwords in VGPRs
    unsigned g[NDW];
    {
        const uint4* gr = (const uint4*)(gp + (size_t)(nv ? n : 0) * WPAD);
        #pragma unroll
        for (int j = 0; j < 9; ++j) {
            uint4 v = gr[j];
            g[4 * j]     = v.x;
            g[4 * j + 1] = v.y;
            g[4 * j + 2] = v.z;
            g[4 * j + 3] = v.w;
        }
        uint4 v9 = gr[9];
        g[36] = v9.x;
        g[37] = v9.y;
    }

    const int row0 = blockIdx.y * ROWS;              // all 4 waves share these rows
    const uint4* mr = (const uint4*)(mp + (size_t)row0 * WPAD);  // blockIdx-uniform address
    float* op = out + (size_t)row0 * NBITS + n;

    #pragma unroll 1
    for (int i = 0; i < ROWS; ++i) {
        uint4 t[10];
        #pragma unroll
        for (int j = 0; j < 10; ++j) t[j] = mr[j];

        unsigned p = 0;
        #pragma unroll
        for (int j = 0; j < 9; ++j) {
            p ^= t[j].x & g[4 * j];
            p ^= t[j].y & g[4 * j + 1];
            p ^= t[j].z & g[4 * j + 2];
            p ^= t[j].w & g[4 * j + 3];
        }
        p ^= t[9].x & g[36];
        p ^= t[9].y & g[37];

        // BPSK: parity 0 -> +1.0, parity 1 -> -1.0 (set sign bit of 1.0f)
        if (nv) *op = __uint_as_float(0x3f800000u | ((unsigned)__popc(p) << 31));

        mr += WPAD / 2;   // 10 uint4 = 160 B = one packed row (was the round-3 bug)
        op += NBITS;
    }
}

// ---------- fallback (only if workspace is too small): direct parity GEMM ----------
__global__ __launch_bounds__(256) void ldpc_naive(const int* __restrict__ m,
                                                  const float* __restrict__ G,
                                                  float* __restrict__ out) {
    long long idx = (long long)blockIdx.x * blockDim.x + threadIdx.x;
    if (idx >= (long long)BATCHN * NBITS) return;
    int b = (int)(idx / NBITS);
    int n = (int)(idx % NBITS);
    int acc = 0;
    const int*   mr = m + (size_t)b * KDIM;
    const float* gr = G + (size_t)n * KDIM;
    for (int k = 0; k < KDIM; ++k)
        acc ^= (mr[k] & (gr[k] != 0.0f ? 1 : 0));
    out[idx] = 1.0f - 2.0f * (float)acc;
}

extern "C" void kernel_launch(void* const* d_in, const int* in_sizes, int n_in,
                              void* d_out, int out_size, void* d_ws, size_t ws_size,
                              hipStream_t stream) {
    const int*   m = (const int*)d_in[0];    // [BATCHN, KDIM] int32 (0/1)
    const float* G = (const float*)d_in[1];  // [NBITS, KDIM]  f32   (0/1)
    float* out = (float*)d_out;              // [BATCHN, NBITS] f32

    const size_t need = ((size_t)BATCHN + NBITS) * WPAD * sizeof(unsigned long long);
    if (ws_size >= need) {
        unsigned long long* mp = (unsigned long long*)d_ws;
        unsigned long long* gp = mp + (size_t)BATCHN * WPAD;

        pack_rows_int  <<<(BATCHN * 64) / 256, 256, 0, stream>>>(m, mp, BATCHN, KDIM);
        pack_rows_float<<<(NBITS  * 64) / 256, 256, 0, stream>>>(G, gp, NBITS, KDIM);

        dim3 grid((NBITS + 255) / 256, BATCHN / ROWS);  // (10, 1024) = 10240 equal blocks
        ldpc_encode<<<grid, 256, 0, stream>>>(mp, gp, out);
    } else {
        long long total = (long long)BATCHN * NBITS;
        ldpc_naive<<<(int)((total + 255) / 256), 256, 0, stream>>>(m, G, out);
    }
}